// Round 3
// baseline (908.341 us; speedup 1.0000x reference)
//
#include <hip/hip_runtime.h>
#include <hip/hip_bf16.h>
#include <cstdint>

#define B_ 4
#define L_ 2048
#define DM 512
#define H_ 8
#define T_ (B_*L_)
#define LDP 72   // padded LDS stride (f16 elems): 144B = 36 banks -> conflict-free-ish

typedef _Float16 f16;
typedef _Float16 f16x8 __attribute__((ext_vector_type(8)));
typedef _Float16 f16x4v __attribute__((ext_vector_type(4)));
typedef float f32x4 __attribute__((ext_vector_type(4)));

// ---------------- mask format detector: 0 = int32, 1 = uint8 ----------------
__global__ void k_detect(const unsigned char* __restrict__ mask, int* __restrict__ flag) {
    __shared__ int s_any;
    if (threadIdx.x == 0) s_any = 0;
    __syncthreads();
    int any = 0;
    for (int i = threadIdx.x; i < 4096; i += 256)
        if ((i & 3) && mask[i]) any = 1;
    if (any) atomicOr(&s_any, 1);
    __syncthreads();
    if (threadIdx.x == 0) *flag = s_any;
}

// ---------------- pack mask -> 1 bit per element via wave ballot ----------------
__global__ void k_packmask(const void* __restrict__ mask, const int* __restrict__ flag,
                           unsigned long long* __restrict__ mw) {
    int gid = blockIdx.x * 256 + threadIdx.x;
    int wid = gid >> 6;
    int lane = gid & 63;
    long long idx = (long long)wid * 64 + lane;
    int v;
    if (*flag) v = ((const unsigned char*)mask)[idx];
    else       v = ((const int*)mask)[idx];
    unsigned long long m = __ballot(v != 0);
    if (lane == 0) mw[wid] = m;
}

// ---------------- f32 -> f16 convert ----------------
__global__ void k_cvt(const float* __restrict__ in, f16* __restrict__ out, int n) {
    int i = (blockIdx.x * 256 + threadIdx.x) * 4;
    if (i >= n) return;
    float4 v = *(const float4*)&in[i];
    f16x4v o = { (f16)v.x, (f16)v.y, (f16)v.z, (f16)v.w };
    *(f16x4v*)&out[i] = o;
}

// ---------------- GEMM: C(M=8192,N=512) = A(M,K=512) * W(N,K)^T + bias ----------------
// LAYOUT 0: write f32 row-major (T,512) to outf
// LAYOUT 1: write f16 head-split (B,H,L,64) to outh
template<int LAYOUT>
__launch_bounds__(256, 2)
__global__ void k_gemm(const f16* __restrict__ A, const f16* __restrict__ W,
                       const float* __restrict__ bias,
                       float* __restrict__ outf, f16* __restrict__ outh) {
    const int K = DM, N = DM;
    __shared__ f16 As[64][LDP];
    __shared__ f16 Ws[64][LDP];
    int m0 = blockIdx.x * 64;
    int n0 = blockIdx.y * 64;
    int t = threadIdx.x;
    int w = t >> 6, l = t & 63;
    int lr = l & 15, lkof = (l >> 4) * 8, lg = (l >> 4) * 4;
    f32x4 acc[4] = {};
    for (int k0 = 0; k0 < K; k0 += 64) {
        __syncthreads();
#pragma unroll
        for (int i = 0; i < 2; ++i) {
            int chunk = t + i * 256;
            int row = chunk >> 3, c8 = (chunk & 7) * 8;
            *(f16x8*)&As[row][c8] = *(const f16x8*)&A[(long long)(m0 + row) * K + k0 + c8];
            *(f16x8*)&Ws[row][c8] = *(const f16x8*)&W[(long long)(n0 + row) * K + k0 + c8];
        }
        __syncthreads();
#pragma unroll
        for (int ks = 0; ks < 2; ++ks) {
            f16x8 a = *(const f16x8*)&As[w * 16 + lr][ks * 32 + lkof];
#pragma unroll
            for (int nt = 0; nt < 4; ++nt) {
                f16x8 b = *(const f16x8*)&Ws[nt * 16 + lr][ks * 32 + lkof];
                acc[nt] = __builtin_amdgcn_mfma_f32_16x16x32_f16(a, b, acc[nt], 0, 0, 0);
            }
        }
    }
#pragma unroll
    for (int nt = 0; nt < 4; ++nt) {
        int j = n0 + nt * 16 + lr;
        float bj = bias[j];
#pragma unroll
        for (int r = 0; r < 4; ++r) {
            int m = m0 + w * 16 + lg + r;
            float v = acc[nt][r] + bj;
            if (LAYOUT == 0) {
                outf[(long long)m * N + j] = v;
            } else {
                int bb = m >> 11, pos = m & (L_ - 1);
                int hh = j >> 6, d = j & 63;
                outh[((long long)(bb * H_ + hh) * L_ + pos) * 64 + d] = (f16)v;
            }
        }
    }
}

// ---------------- fused attention: scores+mask+softmax(online,2-pass)+PV ----------------
__launch_bounds__(256, 2)
__global__ void k_attn(const f16* __restrict__ QH, const f16* __restrict__ KH,
                       const f16* __restrict__ VH, const unsigned long long* __restrict__ mw,
                       float* __restrict__ attn_out, f16* __restrict__ Obuf) {
    __shared__ f16 Qs[64][LDP];
    __shared__ f16 Ks[64][LDP];
    __shared__ f16 Vt[64][LDP];       // V transposed: [dv][lk]
    __shared__ f16 Ps[4][16][LDP];    // per-wave P tile staging
    int bid = blockIdx.x;
    int rb = bid & 31;
    int bh = bid >> 5;
    int b = bh >> 3, h = bh & 7;
    int t = threadIdx.x, w = t >> 6, l = t & 63;
    int lr = l & 15, lkof = (l >> 4) * 8, lg = (l >> 4) * 4;
    const f16* Qp = QH + (long long)bh * L_ * 64 + (long long)rb * 64 * 64;
    const f16* Kp = KH + (long long)bh * L_ * 64;
    const f16* Vp = VH + (long long)bh * L_ * 64;
#pragma unroll
    for (int i = 0; i < 2; ++i) {
        int chunk = t + i * 256;
        int row = chunk >> 3, c8 = (chunk & 7) * 8;
        *(f16x8*)&Qs[row][c8] = *(const f16x8*)&Qp[row * 64 + c8];
    }
    __syncthreads();
    f16x8 qf[2];
    qf[0] = *(const f16x8*)&Qs[w * 16 + lr][lkof];
    qf[1] = *(const f16x8*)&Qs[w * 16 + lr][32 + lkof];

    float mrun[4], lrun[4];
#pragma unroll
    for (int j = 0; j < 4; ++j) { mrun[j] = -1e30f; lrun[j] = 0.f; }
    const unsigned long long* mwrow = mw + ((long long)b * L_ + rb * 64) * (L_ / 64);

    // ---- pass 1: running max & denom ----
    for (int c = 0; c < 32; ++c) {
        __syncthreads();
#pragma unroll
        for (int i = 0; i < 2; ++i) {
            int chunk = t + i * 256;
            int row = chunk >> 3, c8 = (chunk & 7) * 8;
            *(f16x8*)&Ks[row][c8] = *(const f16x8*)&Kp[(c * 64 + row) * 64 + c8];
        }
        __syncthreads();
        f32x4 s[4] = {};
#pragma unroll
        for (int ks = 0; ks < 2; ++ks) {
#pragma unroll
            for (int nt = 0; nt < 4; ++nt) {
                f16x8 bfr = *(const f16x8*)&Ks[nt * 16 + lr][ks * 32 + lkof];
                s[nt] = __builtin_amdgcn_mfma_f32_16x16x32_f16(qf[ks], bfr, s[nt], 0, 0, 0);
            }
        }
#pragma unroll
        for (int j = 0; j < 4; ++j) {
            int lq = w * 16 + lg + j;
            unsigned long long wmask = mwrow[lq * 32 + c];
            float sv[4];
            float mx = -1e30f;
#pragma unroll
            for (int nt = 0; nt < 4; ++nt) {
                float x = s[nt][j] * 0.125f;
                int bit = nt * 16 + lr;
                if ((wmask >> bit) & 1ull) x = -1e30f;
                sv[nt] = x;
                mx = fmaxf(mx, x);
            }
#pragma unroll
            for (int off = 1; off < 16; off <<= 1)
                mx = fmaxf(mx, __shfl_xor(mx, off));
            float mn = fmaxf(mrun[j], mx);
            float sum = 0.f;
#pragma unroll
            for (int nt = 0; nt < 4; ++nt) sum += __expf(sv[nt] - mn);
#pragma unroll
            for (int off = 1; off < 16; off <<= 1)
                sum += __shfl_xor(sum, off);
            lrun[j] = lrun[j] * __expf(mrun[j] - mn) + sum;
            mrun[j] = mn;
        }
    }
    float inv[4];
#pragma unroll
    for (int j = 0; j < 4; ++j) inv[j] = 1.f / lrun[j];

    f32x4 oacc[4] = {};
    float* aout = attn_out + ((long long)(h * B_ + b) * L_ + (long long)rb * 64) * L_;

    // ---- pass 2: write P, accumulate PV ----
    for (int c = 0; c < 32; ++c) {
        __syncthreads();
#pragma unroll
        for (int i = 0; i < 2; ++i) {
            int chunk = t + i * 256;
            int row = chunk >> 3, c8 = (chunk & 7) * 8;
            *(f16x8*)&Ks[row][c8] = *(const f16x8*)&Kp[(c * 64 + row) * 64 + c8];
            f16x8 vv = *(const f16x8*)&Vp[(c * 64 + row) * 64 + c8];
#pragma unroll
            for (int e = 0; e < 8; ++e) Vt[c8 + e][row] = vv[e];
        }
        __syncthreads();
        f32x4 s[4] = {};
#pragma unroll
        for (int ks = 0; ks < 2; ++ks) {
#pragma unroll
            for (int nt = 0; nt < 4; ++nt) {
                f16x8 bfr = *(const f16x8*)&Ks[nt * 16 + lr][ks * 32 + lkof];
                s[nt] = __builtin_amdgcn_mfma_f32_16x16x32_f16(qf[ks], bfr, s[nt], 0, 0, 0);
            }
        }
#pragma unroll
        for (int j = 0; j < 4; ++j) {
            int lq = w * 16 + lg + j;
            unsigned long long wmask = mwrow[lq * 32 + c];
#pragma unroll
            for (int nt = 0; nt < 4; ++nt) {
                float x = s[nt][j] * 0.125f;
                int bit = nt * 16 + lr;
                if ((wmask >> bit) & 1ull) x = -1e30f;
                float p = __expf(x - mrun[j]) * inv[j];
                aout[(long long)lq * L_ + c * 64 + nt * 16 + lr] = p;
                Ps[w][lg + j][nt * 16 + lr] = (f16)p;
            }
        }
        __syncthreads();
#pragma unroll
        for (int ks = 0; ks < 2; ++ks) {
            f16x8 ap = *(const f16x8*)&Ps[w][lr][ks * 32 + lkof];
#pragma unroll
            for (int nt = 0; nt < 4; ++nt) {
                f16x8 bv = *(const f16x8*)&Vt[nt * 16 + lr][ks * 32 + lkof];
                oacc[nt] = __builtin_amdgcn_mfma_f32_16x16x32_f16(ap, bv, oacc[nt], 0, 0, 0);
            }
        }
    }
#pragma unroll
    for (int nt = 0; nt < 4; ++nt) {
#pragma unroll
        for (int r = 0; r < 4; ++r) {
            int lq = rb * 64 + w * 16 + lg + r;
            Obuf[((long long)b * L_ + lq) * DM + h * 64 + nt * 16 + lr] = (f16)oacc[nt][r];
        }
    }
}

// ---------------- residual + LayerNorm ----------------
__global__ void k_ln(const float* __restrict__ fc, const float* __restrict__ res,
                     const float* __restrict__ g, const float* __restrict__ bb,
                     float* __restrict__ out) {
    int row = blockIdx.x * 4 + (threadIdx.x >> 6);
    int l = threadIdx.x & 63;
    const float* x = fc + (size_t)row * DM + l * 8;
    const float* r = res + (size_t)row * DM + l * 8;
    float4 a0 = *(const float4*)x;
    float4 a1 = *(const float4*)(x + 4);
    float4 r0 = *(const float4*)r;
    float4 r1 = *(const float4*)(r + 4);
    float v[8] = {a0.x + r0.x, a0.y + r0.y, a0.z + r0.z, a0.w + r0.w,
                  a1.x + r1.x, a1.y + r1.y, a1.z + r1.z, a1.w + r1.w};
    float s = 0.f, s2 = 0.f;
#pragma unroll
    for (int i = 0; i < 8; ++i) { s += v[i]; s2 += v[i] * v[i]; }
#pragma unroll
    for (int off = 1; off < 64; off <<= 1) {
        s += __shfl_xor(s, off);
        s2 += __shfl_xor(s2, off);
    }
    float mean = s * (1.f / 512.f);
    float var = s2 * (1.f / 512.f) - mean * mean;
    float rstd = rsqrtf(var + 1e-5f);
    const float* gp = g + l * 8;
    const float* bp = bb + l * 8;
    float4 g0 = *(const float4*)gp, g1 = *(const float4*)(gp + 4);
    float4 b0 = *(const float4*)bp, b1 = *(const float4*)(bp + 4);
    float og[8] = {g0.x, g0.y, g0.z, g0.w, g1.x, g1.y, g1.z, g1.w};
    float ob[8] = {b0.x, b0.y, b0.z, b0.w, b1.x, b1.y, b1.z, b1.w};
    float o[8];
#pragma unroll
    for (int i = 0; i < 8; ++i) o[i] = (v[i] - mean) * rstd * og[i] + ob[i];
    float4 w0 = {o[0], o[1], o[2], o[3]};
    float4 w1 = {o[4], o[5], o[6], o[7]};
    float* op = out + (size_t)row * DM + l * 8;
    *(float4*)op = w0;
    *(float4*)(op + 4) = w1;
}

extern "C" void kernel_launch(void* const* d_in, const int* in_sizes, int n_in,
                              void* d_out, int out_size, void* d_ws, size_t ws_size,
                              hipStream_t stream) {
    const float* q    = (const float*)d_in[0];
    const float* k    = (const float*)d_in[1];
    const float* v    = (const float*)d_in[2];
    const void*  mask = d_in[3];
    const float* wq_w = (const float*)d_in[4];
    const float* wq_b = (const float*)d_in[5];
    const float* wk_w = (const float*)d_in[6];
    const float* wk_b = (const float*)d_in[7];
    const float* wv_w = (const float*)d_in[8];
    const float* wv_b = (const float*)d_in[9];
    const float* fc_w = (const float*)d_in[10];
    const float* fc_b = (const float*)d_in[11];
    const float* ln_g = (const float*)d_in[12];
    const float* ln_b = (const float*)d_in[13];

    float* out      = (float*)d_out;
    float* attn_out = out + (size_t)T_ * DM;

    char* ws = (char*)d_ws;
    constexpr size_t SZ_MASKW  = (size_t)B_ * L_ * (L_ / 64) * 8;   // 2 MB
    constexpr size_t SZ_F16_TD = (size_t)T_ * DM * 2;               // 8 MB
    constexpr size_t SZ_F16_W  = (size_t)DM * DM * 2;               // 0.5 MB
    size_t off = 0;
    auto take = [&](size_t bytes) { char* p = ws + off; off = (off + bytes + 255) & ~(size_t)255; return p; };
    unsigned long long* maskw = (unsigned long long*)take(SZ_MASKW);
    int*  flag  = (int*)take(256);
    f16*  qf    = (f16*)take(SZ_F16_TD);
    f16*  kf    = (f16*)take(SZ_F16_TD);
    f16*  vf    = (f16*)take(SZ_F16_TD);
    f16*  wqf   = (f16*)take(SZ_F16_W);
    f16*  wkf   = (f16*)take(SZ_F16_W);
    f16*  wvf   = (f16*)take(SZ_F16_W);
    f16*  fcf   = (f16*)take(SZ_F16_W);
    f16*  QHp   = (f16*)take(SZ_F16_TD);
    f16*  KHp   = (f16*)take(SZ_F16_TD);
    f16*  VHp   = (f16*)take(SZ_F16_TD);
    f16*  Obuf  = (f16*)take(SZ_F16_TD);
    float* FCout = (float*)take((size_t)T_ * DM * 4);
    (void)ws_size; (void)in_sizes; (void)n_in; (void)out_size;

    k_detect<<<1, 256, 0, stream>>>((const unsigned char*)mask, flag);
    k_packmask<<<(B_ * L_ * L_ / 64) / 4, 256, 0, stream>>>(mask, flag, maskw);

    k_cvt<<<(T_ * DM / 4) / 256, 256, 0, stream>>>(q, qf, T_ * DM);
    k_cvt<<<(T_ * DM / 4) / 256, 256, 0, stream>>>(k, kf, T_ * DM);
    k_cvt<<<(T_ * DM / 4) / 256, 256, 0, stream>>>(v, vf, T_ * DM);
    k_cvt<<<(DM * DM / 4) / 256, 256, 0, stream>>>(wq_w, wqf, DM * DM);
    k_cvt<<<(DM * DM / 4) / 256, 256, 0, stream>>>(wk_w, wkf, DM * DM);
    k_cvt<<<(DM * DM / 4) / 256, 256, 0, stream>>>(wv_w, wvf, DM * DM);
    k_cvt<<<(DM * DM / 4) / 256, 256, 0, stream>>>(fc_w, fcf, DM * DM);

    dim3 gg(T_ / 64, DM / 64);
    k_gemm<1><<<gg, 256, 0, stream>>>(qf, wqf, wq_b, nullptr, QHp);
    k_gemm<1><<<gg, 256, 0, stream>>>(kf, wkf, wk_b, nullptr, KHp);
    k_gemm<1><<<gg, 256, 0, stream>>>(vf, wvf, wv_b, nullptr, VHp);

    k_attn<<<B_ * H_ * (L_ / 64), 256, 0, stream>>>(QHp, KHp, VHp, maskw, attn_out, Obuf);

    k_gemm<0><<<gg, 256, 0, stream>>>(Obuf, fcf, fc_b, FCout, nullptr);

    k_ln<<<T_ / 4, 256, 0, stream>>>(FCout, q, ln_g, ln_b, out);
}

// Round 4
// 881.485 us; speedup vs baseline: 1.0305x; 1.0305x over previous
//
#include <hip/hip_runtime.h>
#include <hip/hip_bf16.h>
#include <cstdint>

#define B_ 4
#define L_ 2048
#define DM 512
#define H_ 8
#define T_ (B_*L_)
#define LDP 72   // padded LDS stride (f16 elems)

typedef _Float16 f16;
typedef _Float16 f16x8 __attribute__((ext_vector_type(8)));
typedef _Float16 f16x4v __attribute__((ext_vector_type(4)));
typedef float f32x4 __attribute__((ext_vector_type(4)));

// ---------------- mask format detector: 0 = int32, 1 = uint8 ----------------
__global__ void k_detect(const unsigned char* __restrict__ mask, int* __restrict__ flag) {
    __shared__ int s_any;
    if (threadIdx.x == 0) s_any = 0;
    __syncthreads();
    int any = 0;
    for (int i = threadIdx.x; i < 4096; i += 256)
        if ((i & 3) && mask[i]) any = 1;
    if (any) atomicOr(&s_any, 1);
    __syncthreads();
    if (threadIdx.x == 0) *flag = s_any;
}

// ---------------- pack mask -> 1 bit per element via wave ballot ----------------
__global__ void k_packmask(const void* __restrict__ mask, const int* __restrict__ flag,
                           unsigned long long* __restrict__ mw) {
    int gid = blockIdx.x * 256 + threadIdx.x;
    int wid = gid >> 6;
    int lane = gid & 63;
    long long idx = (long long)wid * 64 + lane;
    int v;
    if (*flag) v = ((const unsigned char*)mask)[idx];
    else       v = ((const int*)mask)[idx];
    unsigned long long m = __ballot(v != 0);
    if (lane == 0) mw[wid] = m;
}

// ---------------- f32 -> f16 convert ----------------
__global__ void k_cvt(const float* __restrict__ in, f16* __restrict__ out, int n) {
    int i = (blockIdx.x * 256 + threadIdx.x) * 4;
    if (i >= n) return;
    float4 v = *(const float4*)&in[i];
    f16x4v o = { (f16)v.x, (f16)v.y, (f16)v.z, (f16)v.w };
    *(f16x4v*)&out[i] = o;
}

// ---------------- GEMM: C(M,N=512) = A(M,K=512) * W(N,K)^T + bias ----------------
// LAYOUT 0: write f32 row-major (T,512); LAYOUT 1: write f16 head-split (B,H,L,64)
template<int LAYOUT>
__launch_bounds__(256, 2)
__global__ void k_gemm(const f16* __restrict__ A, const f16* __restrict__ W,
                       const float* __restrict__ bias,
                       float* __restrict__ outf, f16* __restrict__ outh) {
    const int K = DM, N = DM;
    __shared__ f16 As[64][LDP];
    __shared__ f16 Ws[64][LDP];
    int m0 = blockIdx.x * 64;
    int n0 = blockIdx.y * 64;
    int t = threadIdx.x;
    int w = t >> 6, l = t & 63;
    int lr = l & 15, lkof = (l >> 4) * 8, lg = (l >> 4) * 4;
    f32x4 acc[4] = {};
    int row[2], c8[2];
    f16x8 ar[2], wr[2];
#pragma unroll
    for (int i = 0; i < 2; ++i) {
        int chunk = t + i * 256;
        row[i] = chunk >> 3; c8[i] = (chunk & 7) * 8;
        ar[i] = *(const f16x8*)&A[(long long)(m0 + row[i]) * K + c8[i]];
        wr[i] = *(const f16x8*)&W[(long long)(n0 + row[i]) * K + c8[i]];
    }
    for (int k0 = 0; k0 < K; k0 += 64) {
        __syncthreads();
#pragma unroll
        for (int i = 0; i < 2; ++i) {
            *(f16x8*)&As[row[i]][c8[i]] = ar[i];
            *(f16x8*)&Ws[row[i]][c8[i]] = wr[i];
        }
        __syncthreads();
        if (k0 + 64 < K) {
#pragma unroll
            for (int i = 0; i < 2; ++i) {
                ar[i] = *(const f16x8*)&A[(long long)(m0 + row[i]) * K + k0 + 64 + c8[i]];
                wr[i] = *(const f16x8*)&W[(long long)(n0 + row[i]) * K + k0 + 64 + c8[i]];
            }
        }
#pragma unroll
        for (int ks = 0; ks < 2; ++ks) {
            f16x8 a = *(const f16x8*)&As[w * 16 + lr][ks * 32 + lkof];
#pragma unroll
            for (int nt = 0; nt < 4; ++nt) {
                f16x8 b = *(const f16x8*)&Ws[nt * 16 + lr][ks * 32 + lkof];
                acc[nt] = __builtin_amdgcn_mfma_f32_16x16x32_f16(a, b, acc[nt], 0, 0, 0);
            }
        }
    }
#pragma unroll
    for (int nt = 0; nt < 4; ++nt) {
        int j = n0 + nt * 16 + lr;
        float bj = bias[j];
#pragma unroll
        for (int r = 0; r < 4; ++r) {
            int m = m0 + w * 16 + lg + r;
            float v = acc[nt][r] + bj;
            if (LAYOUT == 0) {
                outf[(long long)m * N + j] = v;
            } else {
                int bb = m >> 11, pos = m & (L_ - 1);
                int hh = j >> 6, d = j & 63;
                outh[((long long)(bb * H_ + hh) * L_ + pos) * 64 + d] = (f16)v;
            }
        }
    }
}

// ---------------- fused attention: static-offset softmax, 2-pass, async staging ----------------
__launch_bounds__(256, 2)
__global__ void k_attn(const f16* __restrict__ QH, const f16* __restrict__ KH,
                       const f16* __restrict__ VH, const unsigned long long* __restrict__ mw,
                       float* __restrict__ attn_out, f16* __restrict__ Obuf) {
    __shared__ f16 Qs[64][LDP];
    __shared__ f16 Ks[64][LDP];
    __shared__ f16 Vt[64][LDP];       // V transposed [dv][k], k XOR-swizzled by ((dv>>3)&7)<<3
    __shared__ f16 Ps[4][16][LDP];    // per-wave normalized-P tile staging
    int bid = blockIdx.x;
    int rb = bid & 31;
    int bh = bid >> 5;
    int b = bh >> 3, h = bh & 7;
    int t = threadIdx.x, w = t >> 6, l = t & 63;
    int lr = l & 15, lkof = (l >> 4) * 8, lg = (l >> 4) * 4;
    const f16* Qp = QH + (long long)bh * L_ * 64 + (long long)rb * 64 * 64;
    const f16* Kp = KH + (long long)bh * L_ * 64;
    const f16* Vp = VH + (long long)bh * L_ * 64;
    int row[2], c8[2];
#pragma unroll
    for (int i = 0; i < 2; ++i) {
        int chunk = t + i * 256;
        row[i] = chunk >> 3; c8[i] = (chunk & 7) * 8;
        *(f16x8*)&Qs[row[i]][c8[i]] = *(const f16x8*)&Qp[row[i] * 64 + c8[i]];
    }
    __syncthreads();
    f16x8 qf[2];
    qf[0] = *(const f16x8*)&Qs[w * 16 + lr][lkof];
    qf[1] = *(const f16x8*)&Qs[w * 16 + lr][32 + lkof];

    float lrun[4] = {0.f, 0.f, 0.f, 0.f};
    const unsigned long long* mwrow = mw + ((long long)b * L_ + rb * 64) * (L_ / 64);

    // ---- pass 1: row sums of exp(x-4) (no max tracking; static offset) ----
    f16x8 kr[2];
#pragma unroll
    for (int i = 0; i < 2; ++i)
        kr[i] = *(const f16x8*)&Kp[row[i] * 64 + c8[i]];
    for (int c = 0; c < 32; ++c) {
        __syncthreads();
#pragma unroll
        for (int i = 0; i < 2; ++i)
            *(f16x8*)&Ks[row[i]][c8[i]] = kr[i];
        __syncthreads();
        if (c < 31) {
#pragma unroll
            for (int i = 0; i < 2; ++i)
                kr[i] = *(const f16x8*)&Kp[((c + 1) * 64 + row[i]) * 64 + c8[i]];
        }
        f32x4 s[4] = {};
#pragma unroll
        for (int ks = 0; ks < 2; ++ks) {
#pragma unroll
            for (int nt = 0; nt < 4; ++nt) {
                f16x8 bfr = *(const f16x8*)&Ks[nt * 16 + lr][ks * 32 + lkof];
                s[nt] = __builtin_amdgcn_mfma_f32_16x16x32_f16(qf[ks], bfr, s[nt], 0, 0, 0);
            }
        }
#pragma unroll
        for (int j = 0; j < 4; ++j) {
            int lq = w * 16 + lg + j;
            unsigned long long wmask = mwrow[lq * 32 + c];
            float sum = 0.f;
#pragma unroll
            for (int nt = 0; nt < 4; ++nt) {
                int bit = nt * 16 + lr;
                float e = ((wmask >> bit) & 1ull) ? 0.f : __expf(s[nt][j] * 0.125f - 4.f);
                sum += e;
            }
#pragma unroll
            for (int off = 1; off < 16; off <<= 1)
                sum += __shfl_xor(sum, off);
            lrun[j] += sum;
        }
    }
    float inv[4];
#pragma unroll
    for (int j = 0; j < 4; ++j) inv[j] = 1.f / lrun[j];

    f32x4 oacc[4] = {};
    float* aout = attn_out + ((long long)(h * B_ + b) * L_ + (long long)rb * 64) * L_;

    // ---- pass 2: recompute scores, write normalized P, accumulate PV ----
    f16x8 vr[2];
#pragma unroll
    for (int i = 0; i < 2; ++i) {
        kr[i] = *(const f16x8*)&Kp[row[i] * 64 + c8[i]];
        vr[i] = *(const f16x8*)&Vp[row[i] * 64 + c8[i]];
    }
    for (int c = 0; c < 32; ++c) {
        __syncthreads();
#pragma unroll
        for (int i = 0; i < 2; ++i) {
            *(f16x8*)&Ks[row[i]][c8[i]] = kr[i];
            int kx = (c8[i] >> 3) << 3;   // ((dv>>3)&7)<<3, dv = c8[i]+ee (ee<8)
#pragma unroll
            for (int ee = 0; ee < 8; ++ee)
                Vt[c8[i] + ee][row[i] ^ (kx & 56)] = vr[i][ee];
        }
        __syncthreads();
        if (c < 31) {
#pragma unroll
            for (int i = 0; i < 2; ++i) {
                kr[i] = *(const f16x8*)&Kp[((c + 1) * 64 + row[i]) * 64 + c8[i]];
                vr[i] = *(const f16x8*)&Vp[((c + 1) * 64 + row[i]) * 64 + c8[i]];
            }
        }
        f32x4 s[4] = {};
#pragma unroll
        for (int ks = 0; ks < 2; ++ks) {
#pragma unroll
            for (int nt = 0; nt < 4; ++nt) {
                f16x8 bfr = *(const f16x8*)&Ks[nt * 16 + lr][ks * 32 + lkof];
                s[nt] = __builtin_amdgcn_mfma_f32_16x16x32_f16(qf[ks], bfr, s[nt], 0, 0, 0);
            }
        }
#pragma unroll
        for (int j = 0; j < 4; ++j) {
            int lq = w * 16 + lg + j;
            unsigned long long wmask = mwrow[lq * 32 + c];
#pragma unroll
            for (int nt = 0; nt < 4; ++nt) {
                int bit = nt * 16 + lr;
                float e = ((wmask >> bit) & 1ull) ? 0.f : __expf(s[nt][j] * 0.125f - 4.f);
                float p = e * inv[j];
                aout[(long long)lq * L_ + c * 64 + nt * 16 + lr] = p;
                Ps[w][lg + j][nt * 16 + lr] = (f16)p;
            }
        }
        __syncthreads();
#pragma unroll
        for (int ks = 0; ks < 2; ++ks) {
            f16x8 ap = *(const f16x8*)&Ps[w][lr][ks * 32 + lkof];
#pragma unroll
            for (int nt = 0; nt < 4; ++nt) {
                int r = nt * 16 + lr;
                int kxr = ((r >> 3) & 7) << 3;
                f16x8 bv = *(const f16x8*)&Vt[r][(ks * 32 + lkof) ^ kxr];
                oacc[nt] = __builtin_amdgcn_mfma_f32_16x16x32_f16(ap, bv, oacc[nt], 0, 0, 0);
            }
        }
    }
#pragma unroll
    for (int nt = 0; nt < 4; ++nt) {
#pragma unroll
        for (int r = 0; r < 4; ++r) {
            int lq = rb * 64 + w * 16 + lg + r;
            Obuf[((long long)b * L_ + lq) * DM + h * 64 + nt * 16 + lr] = (f16)oacc[nt][r];
        }
    }
}

// ---------------- residual + LayerNorm ----------------
__global__ void k_ln(const float* __restrict__ fc, const float* __restrict__ res,
                     const float* __restrict__ g, const float* __restrict__ bb,
                     float* __restrict__ out) {
    int row = blockIdx.x * 4 + (threadIdx.x >> 6);
    int l = threadIdx.x & 63;
    const float* x = fc + (size_t)row * DM + l * 8;
    const float* r = res + (size_t)row * DM + l * 8;
    float4 a0 = *(const float4*)x;
    float4 a1 = *(const float4*)(x + 4);
    float4 r0 = *(const float4*)r;
    float4 r1 = *(const float4*)(r + 4);
    float v[8] = {a0.x + r0.x, a0.y + r0.y, a0.z + r0.z, a0.w + r0.w,
                  a1.x + r1.x, a1.y + r1.y, a1.z + r1.z, a1.w + r1.w};
    float s = 0.f, s2 = 0.f;
#pragma unroll
    for (int i = 0; i < 8; ++i) { s += v[i]; s2 += v[i] * v[i]; }
#pragma unroll
    for (int off = 1; off < 64; off <<= 1) {
        s += __shfl_xor(s, off);
        s2 += __shfl_xor(s2, off);
    }
    float mean = s * (1.f / 512.f);
    float var = s2 * (1.f / 512.f) - mean * mean;
    float rstd = rsqrtf(var + 1e-5f);
    const float* gp = g + l * 8;
    const float* bp = bb + l * 8;
    float4 g0 = *(const float4*)gp, g1 = *(const float4*)(gp + 4);
    float4 b0 = *(const float4*)bp, b1 = *(const float4*)(bp + 4);
    float og[8] = {g0.x, g0.y, g0.z, g0.w, g1.x, g1.y, g1.z, g1.w};
    float ob[8] = {b0.x, b0.y, b0.z, b0.w, b1.x, b1.y, b1.z, b1.w};
    float o[8];
#pragma unroll
    for (int i = 0; i < 8; ++i) o[i] = (v[i] - mean) * rstd * og[i] + ob[i];
    float4 w0 = {o[0], o[1], o[2], o[3]};
    float4 w1 = {o[4], o[5], o[6], o[7]};
    float* op = out + (size_t)row * DM + l * 8;
    *(float4*)op = w0;
    *(float4*)(op + 4) = w1;
}

extern "C" void kernel_launch(void* const* d_in, const int* in_sizes, int n_in,
                              void* d_out, int out_size, void* d_ws, size_t ws_size,
                              hipStream_t stream) {
    const float* q    = (const float*)d_in[0];
    const float* k    = (const float*)d_in[1];
    const float* v    = (const float*)d_in[2];
    const void*  mask = d_in[3];
    const float* wq_w = (const float*)d_in[4];
    const float* wq_b = (const float*)d_in[5];
    const float* wk_w = (const float*)d_in[6];
    const float* wk_b = (const float*)d_in[7];
    const float* wv_w = (const float*)d_in[8];
    const float* wv_b = (const float*)d_in[9];
    const float* fc_w = (const float*)d_in[10];
    const float* fc_b = (const float*)d_in[11];
    const float* ln_g = (const float*)d_in[12];
    const float* ln_b = (const float*)d_in[13];

    float* out      = (float*)d_out;
    float* attn_out = out + (size_t)T_ * DM;

    char* ws = (char*)d_ws;
    constexpr size_t SZ_MASKW  = (size_t)B_ * L_ * (L_ / 64) * 8;   // 2 MB
    constexpr size_t SZ_F16_TD = (size_t)T_ * DM * 2;               // 8 MB
    constexpr size_t SZ_F16_W  = (size_t)DM * DM * 2;               // 0.5 MB
    size_t off = 0;
    auto take = [&](size_t bytes) { char* p = ws + off; off = (off + bytes + 255) & ~(size_t)255; return p; };
    unsigned long long* maskw = (unsigned long long*)take(SZ_MASKW);
    int*  flag  = (int*)take(256);
    f16*  qf    = (f16*)take(SZ_F16_TD);
    f16*  kf    = (f16*)take(SZ_F16_TD);
    f16*  vf    = (f16*)take(SZ_F16_TD);
    f16*  wqf   = (f16*)take(SZ_F16_W);
    f16*  wkf   = (f16*)take(SZ_F16_W);
    f16*  wvf   = (f16*)take(SZ_F16_W);
    f16*  fcf   = (f16*)take(SZ_F16_W);
    f16*  QHp   = (f16*)take(SZ_F16_TD);
    f16*  KHp   = (f16*)take(SZ_F16_TD);
    f16*  VHp   = (f16*)take(SZ_F16_TD);
    f16*  Obuf  = (f16*)take(SZ_F16_TD);
    float* FCout = (float*)take((size_t)T_ * DM * 4);
    (void)ws_size; (void)in_sizes; (void)n_in; (void)out_size;

    k_detect<<<1, 256, 0, stream>>>((const unsigned char*)mask, flag);
    k_packmask<<<(B_ * L_ * L_ / 64) / 4, 256, 0, stream>>>(mask, flag, maskw);

    k_cvt<<<(T_ * DM / 4) / 256, 256, 0, stream>>>(q, qf, T_ * DM);
    k_cvt<<<(T_ * DM / 4) / 256, 256, 0, stream>>>(k, kf, T_ * DM);
    k_cvt<<<(T_ * DM / 4) / 256, 256, 0, stream>>>(v, vf, T_ * DM);
    k_cvt<<<(DM * DM / 4) / 256, 256, 0, stream>>>(wq_w, wqf, DM * DM);
    k_cvt<<<(DM * DM / 4) / 256, 256, 0, stream>>>(wk_w, wkf, DM * DM);
    k_cvt<<<(DM * DM / 4) / 256, 256, 0, stream>>>(wv_w, wvf, DM * DM);
    k_cvt<<<(DM * DM / 4) / 256, 256, 0, stream>>>(fc_w, fcf, DM * DM);

    dim3 gg(T_ / 64, DM / 64);
    k_gemm<1><<<gg, 256, 0, stream>>>(qf, wqf, wq_b, nullptr, QHp);
    k_gemm<1><<<gg, 256, 0, stream>>>(kf, wkf, wk_b, nullptr, KHp);
    k_gemm<1><<<gg, 256, 0, stream>>>(vf, wvf, wv_b, nullptr, VHp);

    k_attn<<<B_ * H_ * (L_ / 64), 256, 0, stream>>>(QHp, KHp, VHp, maskw, attn_out, Obuf);

    k_gemm<0><<<gg, 256, 0, stream>>>(Obuf, fcf, fc_b, FCout, nullptr);

    k_ln<<<T_ / 4, 256, 0, stream>>>(FCout, q, ln_g, ln_b, out);
}

// Round 5
// 850.716 us; speedup vs baseline: 1.0677x; 1.0362x over previous
//
#include <hip/hip_runtime.h>
#include <hip/hip_bf16.h>
#include <cstdint>

#define B_ 4
#define L_ 2048
#define DM 512
#define H_ 8
#define T_ (B_*L_)
#define LDP 72   // padded LDS stride (f16 elems) for attn tiles

typedef _Float16 f16;
typedef _Float16 f16x8 __attribute__((ext_vector_type(8)));
typedef _Float16 f16x4v __attribute__((ext_vector_type(4)));
typedef float f32x4 __attribute__((ext_vector_type(4)));

#define GLOAD16(gp, lp) __builtin_amdgcn_global_load_lds( \
    (const __attribute__((address_space(1))) void*)(gp),  \
    (__attribute__((address_space(3))) void*)(lp), 16, 0, 0)

// ---------------- mask format detector: 0 = int32, 1 = uint8 ----------------
__global__ void k_detect(const unsigned char* __restrict__ mask, int* __restrict__ flag) {
    __shared__ int s_any;
    if (threadIdx.x == 0) s_any = 0;
    __syncthreads();
    int any = 0;
    for (int i = threadIdx.x; i < 4096; i += 256)
        if ((i & 3) && mask[i]) any = 1;
    if (any) atomicOr(&s_any, 1);
    __syncthreads();
    if (threadIdx.x == 0) *flag = s_any;
}

// ---------------- pack mask -> 1 bit per element via wave ballot ----------------
__global__ void k_packmask(const void* __restrict__ mask, const int* __restrict__ flag,
                           unsigned long long* __restrict__ mw) {
    int gid = blockIdx.x * 256 + threadIdx.x;
    int wid = gid >> 6;
    int lane = gid & 63;
    long long idx = (long long)wid * 64 + lane;
    int v;
    if (*flag) v = ((const unsigned char*)mask)[idx];
    else       v = ((const int*)mask)[idx];
    unsigned long long m = __ballot(v != 0);
    if (lane == 0) mw[wid] = m;
}

// ---------------- f32 -> f16 converts (merged launches) ----------------
__global__ void k_cvt3(const float* __restrict__ a, const float* __restrict__ b,
                       const float* __restrict__ c,
                       f16* __restrict__ oa, f16* __restrict__ ob, f16* __restrict__ oc) {
    int i = (blockIdx.x * 256 + threadIdx.x) * 4;
    const float* src = blockIdx.y == 0 ? a : blockIdx.y == 1 ? b : c;
    f16* dst = blockIdx.y == 0 ? oa : blockIdx.y == 1 ? ob : oc;
    float4 v = *(const float4*)&src[i];
    f16x4v o = { (f16)v.x, (f16)v.y, (f16)v.z, (f16)v.w };
    *(f16x4v*)&dst[i] = o;
}
__global__ void k_cvt4(const float* __restrict__ a, const float* __restrict__ b,
                       const float* __restrict__ c, const float* __restrict__ d,
                       f16* __restrict__ oa, f16* __restrict__ ob,
                       f16* __restrict__ oc, f16* __restrict__ od) {
    int i = (blockIdx.x * 256 + threadIdx.x) * 4;
    const float* src = blockIdx.y == 0 ? a : blockIdx.y == 1 ? b : blockIdx.y == 2 ? c : d;
    f16* dst = blockIdx.y == 0 ? oa : blockIdx.y == 1 ? ob : blockIdx.y == 2 ? oc : od;
    float4 v = *(const float4*)&src[i];
    f16x4v o = { (f16)v.x, (f16)v.y, (f16)v.z, (f16)v.w };
    *(f16x4v*)&dst[i] = o;
}

// ---------------- GEMM (m97-class): C(M,N=512) = A(M,K=512)*W(N,K)^T + bias ----
// BM=128 BN=64 BK=64, dbuf LDS, global_load_lds 16B, XOR-swizzled LDS reads.
// LAYOUT 0: f32 row-major (T,512) -> outf; LAYOUT 1: f16 head-split (B,H,L,64) -> outh
template<int LAYOUT>
__launch_bounds__(256, 2)
__global__ void k_gemm2(const f16* __restrict__ A, const f16* __restrict__ W,
                        const float* __restrict__ bias,
                        float* __restrict__ outf, f16* __restrict__ outh) {
    constexpr int K = DM;
    __shared__ f16 As[2][128 * 64];
    __shared__ f16 Ws[2][64 * 64];
    const int m0 = blockIdx.x * 128;
    const int n0 = blockIdx.y * 64;
    const int t = threadIdx.x;
    const int wv = t >> 6, l = t & 63;
    const int lr = l & 15, g = l >> 4, lg = g * 4;
    const int sr = l >> 3;              // staging sub-row 0..7
    const int sc = 8 * ((l & 7) ^ sr);  // inverse-swizzled source col (f16)
    f32x4 acc[2][4] = {};

    auto stage = [&](int buf, int kt) {
        const long long k0 = kt * 64;
#pragma unroll
        for (int j = 0; j < 4; ++j) {
            int r = wv * 32 + j * 8;
            GLOAD16(A + (long long)(m0 + r + sr) * K + k0 + sc, &As[buf][r * 64]);
        }
#pragma unroll
        for (int j = 0; j < 2; ++j) {
            int r = wv * 16 + j * 8;
            GLOAD16(W + (long long)(n0 + r + sr) * K + k0 + sc, &Ws[buf][r * 64]);
        }
    };

    stage(0, 0);
    __syncthreads();
    for (int kt = 0; kt < 8; ++kt) {
        const int cur = kt & 1;
        if (kt < 7) stage(cur ^ 1, kt + 1);
#pragma unroll
        for (int ks = 0; ks < 2; ++ks) {
            f16x8 af[2];
#pragma unroll
            for (int mt = 0; mt < 2; ++mt) {
                int row = wv * 32 + mt * 16 + lr;
                af[mt] = *(const f16x8*)&As[cur][row * 64 + ((ks * 32 + g * 8) ^ ((row & 7) << 3))];
            }
#pragma unroll
            for (int nt = 0; nt < 4; ++nt) {
                int row = nt * 16 + lr;
                f16x8 bf = *(const f16x8*)&Ws[cur][row * 64 + ((ks * 32 + g * 8) ^ ((row & 7) << 3))];
#pragma unroll
                for (int mt = 0; mt < 2; ++mt)
                    acc[mt][nt] = __builtin_amdgcn_mfma_f32_16x16x32_f16(af[mt], bf, acc[mt][nt], 0, 0, 0);
            }
        }
        __syncthreads();
    }
#pragma unroll
    for (int nt = 0; nt < 4; ++nt) {
        int j = n0 + nt * 16 + lr;
        float bj = bias[j];
#pragma unroll
        for (int mt = 0; mt < 2; ++mt) {
#pragma unroll
            for (int r = 0; r < 4; ++r) {
                int m = m0 + wv * 32 + mt * 16 + lg + r;
                float vv = acc[mt][nt][r] + bj;
                if (LAYOUT == 0) {
                    outf[(long long)m * DM + j] = vv;
                } else {
                    int bb = m >> 11, pos = m & (L_ - 1);
                    outh[((long long)(bb * H_ + (j >> 6)) * L_ + pos) * 64 + (j & 63)] = (f16)vv;
                }
            }
        }
    }
}

// ---------------- fused attention: static-offset softmax, 2-pass, async staging ----------------
__launch_bounds__(256, 2)
__global__ void k_attn(const f16* __restrict__ QH, const f16* __restrict__ KH,
                       const f16* __restrict__ VH, const unsigned long long* __restrict__ mw,
                       float* __restrict__ attn_out, f16* __restrict__ Obuf) {
    __shared__ f16 Qs[64][LDP];
    __shared__ f16 Ks[64][LDP];
    __shared__ f16 Vt[64][LDP];       // V transposed [dv][k], k XOR-swizzled by ((dv>>3)&7)<<3
    __shared__ f16 Ps[4][16][LDP];    // per-wave normalized-P tile staging (wave-local!)
    int bid = blockIdx.x;
    int rb = bid & 31;
    int bh = bid >> 5;
    int b = bh >> 3, h = bh & 7;
    int t = threadIdx.x, w = t >> 6, l = t & 63;
    int lr = l & 15, lkof = (l >> 4) * 8, lg = (l >> 4) * 4;
    const f16* Qp = QH + (long long)bh * L_ * 64 + (long long)rb * 64 * 64;
    const f16* Kp = KH + (long long)bh * L_ * 64;
    const f16* Vp = VH + (long long)bh * L_ * 64;
    int row[2], c8[2];
#pragma unroll
    for (int i = 0; i < 2; ++i) {
        int chunk = t + i * 256;
        row[i] = chunk >> 3; c8[i] = (chunk & 7) * 8;
        *(f16x8*)&Qs[row[i]][c8[i]] = *(const f16x8*)&Qp[row[i] * 64 + c8[i]];
    }
    __syncthreads();
    f16x8 qf[2];
    qf[0] = *(const f16x8*)&Qs[w * 16 + lr][lkof];
    qf[1] = *(const f16x8*)&Qs[w * 16 + lr][32 + lkof];

    float lrun[4] = {0.f, 0.f, 0.f, 0.f};
    const unsigned long long* mwrow = mw + ((long long)b * L_ + rb * 64) * (L_ / 64);

    // ---- pass 1: row sums of exp(x-4) (no max tracking; static offset) ----
    f16x8 kr[2];
#pragma unroll
    for (int i = 0; i < 2; ++i)
        kr[i] = *(const f16x8*)&Kp[row[i] * 64 + c8[i]];
    for (int c = 0; c < 32; ++c) {
        __syncthreads();
#pragma unroll
        for (int i = 0; i < 2; ++i)
            *(f16x8*)&Ks[row[i]][c8[i]] = kr[i];
        __syncthreads();
        if (c < 31) {
#pragma unroll
            for (int i = 0; i < 2; ++i)
                kr[i] = *(const f16x8*)&Kp[((c + 1) * 64 + row[i]) * 64 + c8[i]];
        }
        f32x4 s[4] = {};
#pragma unroll
        for (int ks = 0; ks < 2; ++ks) {
#pragma unroll
            for (int nt = 0; nt < 4; ++nt) {
                f16x8 bfr = *(const f16x8*)&Ks[nt * 16 + lr][ks * 32 + lkof];
                s[nt] = __builtin_amdgcn_mfma_f32_16x16x32_f16(qf[ks], bfr, s[nt], 0, 0, 0);
            }
        }
#pragma unroll
        for (int j = 0; j < 4; ++j) {
            int lq = w * 16 + lg + j;
            unsigned long long wmask = mwrow[lq * 32 + c];
            float sum = 0.f;
#pragma unroll
            for (int nt = 0; nt < 4; ++nt) {
                int bit = nt * 16 + lr;
                float e = ((wmask >> bit) & 1ull) ? 0.f : __expf(s[nt][j] * 0.125f - 4.f);
                sum += e;
            }
#pragma unroll
            for (int off = 1; off < 16; off <<= 1)
                sum += __shfl_xor(sum, off);
            lrun[j] += sum;
        }
    }
    float inv[4];
#pragma unroll
    for (int j = 0; j < 4; ++j) inv[j] = 1.f / lrun[j];

    f32x4 oacc[4] = {};
    float* aout = attn_out + ((long long)(h * B_ + b) * L_ + (long long)rb * 64) * L_;

    // ---- pass 2: recompute scores, write normalized P, accumulate PV ----
    f16x8 vr[2];
#pragma unroll
    for (int i = 0; i < 2; ++i) {
        kr[i] = *(const f16x8*)&Kp[row[i] * 64 + c8[i]];
        vr[i] = *(const f16x8*)&Vp[row[i] * 64 + c8[i]];
    }
    for (int c = 0; c < 32; ++c) {
        __syncthreads();
#pragma unroll
        for (int i = 0; i < 2; ++i) {
            *(f16x8*)&Ks[row[i]][c8[i]] = kr[i];
            int kx = (c8[i] >> 3) << 3;
#pragma unroll
            for (int ee = 0; ee < 8; ++ee)
                Vt[c8[i] + ee][row[i] ^ (kx & 56)] = vr[i][ee];
        }
        __syncthreads();
        if (c < 31) {
#pragma unroll
            for (int i = 0; i < 2; ++i) {
                kr[i] = *(const f16x8*)&Kp[((c + 1) * 64 + row[i]) * 64 + c8[i]];
                vr[i] = *(const f16x8*)&Vp[((c + 1) * 64 + row[i]) * 64 + c8[i]];
            }
        }
        f32x4 s[4] = {};
#pragma unroll
        for (int ks = 0; ks < 2; ++ks) {
#pragma unroll
            for (int nt = 0; nt < 4; ++nt) {
                f16x8 bfr = *(const f16x8*)&Ks[nt * 16 + lr][ks * 32 + lkof];
                s[nt] = __builtin_amdgcn_mfma_f32_16x16x32_f16(qf[ks], bfr, s[nt], 0, 0, 0);
            }
        }
#pragma unroll
        for (int j = 0; j < 4; ++j) {
            int lq = w * 16 + lg + j;
            unsigned long long wmask = mwrow[lq * 32 + c];
#pragma unroll
            for (int nt = 0; nt < 4; ++nt) {
                int bit = nt * 16 + lr;
                float e = ((wmask >> bit) & 1ull) ? 0.f : __expf(s[nt][j] * 0.125f - 4.f);
                float p = e * inv[j];
                aout[(long long)lq * L_ + c * 64 + nt * 16 + lr] = p;
                Ps[w][lg + j][nt * 16 + lr] = (f16)p;
            }
        }
        // Ps is strictly wave-local (indexed [w]); a block barrier is overkill.
        // Drain this wave's ds_writes, then fence the scheduler (rule #18).
        asm volatile("s_waitcnt lgkmcnt(0)" ::: "memory");
        __builtin_amdgcn_sched_barrier(0);
#pragma unroll
        for (int ks = 0; ks < 2; ++ks) {
            f16x8 ap = *(const f16x8*)&Ps[w][lr][ks * 32 + lkof];
#pragma unroll
            for (int nt = 0; nt < 4; ++nt) {
                int r = nt * 16 + lr;
                int kxr = ((r >> 3) & 7) << 3;
                f16x8 bv = *(const f16x8*)&Vt[r][(ks * 32 + lkof) ^ kxr];
                oacc[nt] = __builtin_amdgcn_mfma_f32_16x16x32_f16(ap, bv, oacc[nt], 0, 0, 0);
            }
        }
    }
#pragma unroll
    for (int nt = 0; nt < 4; ++nt) {
#pragma unroll
        for (int r = 0; r < 4; ++r) {
            int lq = rb * 64 + w * 16 + lg + r;
            Obuf[((long long)b * L_ + lq) * DM + h * 64 + nt * 16 + lr] = (f16)oacc[nt][r];
        }
    }
}

// ---------------- residual + LayerNorm ----------------
__global__ void k_ln(const float* __restrict__ fc, const float* __restrict__ res,
                     const float* __restrict__ g, const float* __restrict__ bb,
                     float* __restrict__ out) {
    int row = blockIdx.x * 4 + (threadIdx.x >> 6);
    int l = threadIdx.x & 63;
    const float* x = fc + (size_t)row * DM + l * 8;
    const float* r = res + (size_t)row * DM + l * 8;
    float4 a0 = *(const float4*)x;
    float4 a1 = *(const float4*)(x + 4);
    float4 r0 = *(const float4*)r;
    float4 r1 = *(const float4*)(r + 4);
    float v[8] = {a0.x + r0.x, a0.y + r0.y, a0.z + r0.z, a0.w + r0.w,
                  a1.x + r1.x, a1.y + r1.y, a1.z + r1.z, a1.w + r1.w};
    float s = 0.f, s2 = 0.f;
#pragma unroll
    for (int i = 0; i < 8; ++i) { s += v[i]; s2 += v[i] * v[i]; }
#pragma unroll
    for (int off = 1; off < 64; off <<= 1) {
        s += __shfl_xor(s, off);
        s2 += __shfl_xor(s2, off);
    }
    float mean = s * (1.f / 512.f);
    float var = s2 * (1.f / 512.f) - mean * mean;
    float rstd = rsqrtf(var + 1e-5f);
    const float* gp = g + l * 8;
    const float* bp = bb + l * 8;
    float4 g0 = *(const float4*)gp, g1 = *(const float4*)(gp + 4);
    float4 b0 = *(const float4*)bp, b1 = *(const float4*)(bp + 4);
    float og[8] = {g0.x, g0.y, g0.z, g0.w, g1.x, g1.y, g1.z, g1.w};
    float ob[8] = {b0.x, b0.y, b0.z, b0.w, b1.x, b1.y, b1.z, b1.w};
    float o[8];
#pragma unroll
    for (int i = 0; i < 8; ++i) o[i] = (v[i] - mean) * rstd * og[i] + ob[i];
    float4 w0 = {o[0], o[1], o[2], o[3]};
    float4 w1 = {o[4], o[5], o[6], o[7]};
    float* op = out + (size_t)row * DM + l * 8;
    *(float4*)op = w0;
    *(float4*)(op + 4) = w1;
}

extern "C" void kernel_launch(void* const* d_in, const int* in_sizes, int n_in,
                              void* d_out, int out_size, void* d_ws, size_t ws_size,
                              hipStream_t stream) {
    const float* q    = (const float*)d_in[0];
    const float* k    = (const float*)d_in[1];
    const float* v    = (const float*)d_in[2];
    const void*  mask = d_in[3];
    const float* wq_w = (const float*)d_in[4];
    const float* wq_b = (const float*)d_in[5];
    const float* wk_w = (const float*)d_in[6];
    const float* wk_b = (const float*)d_in[7];
    const float* wv_w = (const float*)d_in[8];
    const float* wv_b = (const float*)d_in[9];
    const float* fc_w = (const float*)d_in[10];
    const float* fc_b = (const float*)d_in[11];
    const float* ln_g = (const float*)d_in[12];
    const float* ln_b = (const float*)d_in[13];

    float* out      = (float*)d_out;
    float* attn_out = out + (size_t)T_ * DM;

    char* ws = (char*)d_ws;
    constexpr size_t SZ_MASKW  = (size_t)B_ * L_ * (L_ / 64) * 8;   // 2 MB
    constexpr size_t SZ_F16_TD = (size_t)T_ * DM * 2;               // 8 MB
    constexpr size_t SZ_F16_W  = (size_t)DM * DM * 2;               // 0.5 MB
    size_t off = 0;
    auto take = [&](size_t bytes) { char* p = ws + off; off = (off + bytes + 255) & ~(size_t)255; return p; };
    unsigned long long* maskw = (unsigned long long*)take(SZ_MASKW);
    int*  flag  = (int*)take(256);
    f16*  qf    = (f16*)take(SZ_F16_TD);
    f16*  kf    = (f16*)take(SZ_F16_TD);
    f16*  vf    = (f16*)take(SZ_F16_TD);
    f16*  wqf   = (f16*)take(SZ_F16_W);
    f16*  wkf   = (f16*)take(SZ_F16_W);
    f16*  wvf   = (f16*)take(SZ_F16_W);
    f16*  fcf   = (f16*)take(SZ_F16_W);
    f16*  QHp   = (f16*)take(SZ_F16_TD);
    f16*  KHp   = (f16*)take(SZ_F16_TD);
    f16*  VHp   = (f16*)take(SZ_F16_TD);
    f16*  Obuf  = (f16*)take(SZ_F16_TD);
    float* FCout = (float*)take((size_t)T_ * DM * 4);
    (void)ws_size; (void)in_sizes; (void)n_in; (void)out_size;

    k_detect<<<1, 256, 0, stream>>>((const unsigned char*)mask, flag);
    k_packmask<<<(B_ * L_ * L_ / 64) / 4, 256, 0, stream>>>(mask, flag, maskw);

    dim3 g3((T_ * DM / 4) / 256, 3);
    k_cvt3<<<g3, 256, 0, stream>>>(q, k, v, qf, kf, vf);
    dim3 g4((DM * DM / 4) / 256, 4);
    k_cvt4<<<g4, 256, 0, stream>>>(wq_w, wk_w, wv_w, fc_w, wqf, wkf, wvf, fcf);

    dim3 gg(T_ / 128, DM / 64);
    k_gemm2<1><<<gg, 256, 0, stream>>>(qf, wqf, wq_b, nullptr, QHp);
    k_gemm2<1><<<gg, 256, 0, stream>>>(kf, wkf, wk_b, nullptr, KHp);
    k_gemm2<1><<<gg, 256, 0, stream>>>(vf, wvf, wv_b, nullptr, VHp);

    k_attn<<<B_ * H_ * (L_ / 64), 256, 0, stream>>>(QHp, KHp, VHp, maskw, attn_out, Obuf);

    k_gemm2<0><<<gg, 256, 0, stream>>>(Obuf, fcf, fc_b, FCout, nullptr);

    k_ln<<<T_ / 4, 256, 0, stream>>>(FCout, q, ln_g, ln_b, out);
}